// Round 1
// baseline (47.214 us; speedup 1.0000x reference)
//
#include <hip/hip_runtime.h>
#include <math.h>

#define BLOCK 256
#define R 8                 // pred points per thread (in registers)
#define APB (BLOCK * R)     // 2048 a-points per block
#define MCHUNK 512          // target points staged per block
#define NPTS 8192
#define NBATCH 4

// Direction pass: for each a-point i in this block's chunk, compute
// min over this block's b-chunk of (d2 - a2_i) = fma(ax,u, fma(ay,v,w)),
// then add a2_i back, clamp >= 0, atomicMin (uint bits) into minbuf.
__global__ __launch_bounds__(BLOCK) void hausdorff_min_kernel(
    const float* __restrict__ pred, const float* __restrict__ targ,
    unsigned int* __restrict__ minbits /* [B][2][NPTS] */)
{
    const int ACH = NPTS / APB;     // 4
    const int MCH = NPTS / MCHUNK;  // 16

    int bid = blockIdx.x;
    int mchunk = bid % MCH; bid /= MCH;
    int achunk = bid % ACH; bid /= ACH;
    int dir    = bid % 2;   bid /= 2;
    int batch  = bid;               // 0..3

    const float* Apts = (dir == 0) ? pred : targ;
    const float* Bpts = (dir == 0) ? targ : pred;
    const float* a  = Apts + (size_t)batch * NPTS * 2;
    const float* bp = Bpts + (size_t)batch * NPTS * 2;

    __shared__ float4 sb[MCHUNK];   // (u=-2bx, v=-2by, w=b2, pad)

    // Stage MCHUNK target points: 512 points = 256 float4 loads (2 pts each)
    {
        const float4* src = reinterpret_cast<const float4*>(bp + mchunk * MCHUNK * 2);
        float4 p = src[threadIdx.x];
        sb[2 * threadIdx.x]     = make_float4(-2.f * p.x, -2.f * p.y,
                                              fmaf(p.x, p.x, p.y * p.y), 0.f);
        sb[2 * threadIdx.x + 1] = make_float4(-2.f * p.z, -2.f * p.w,
                                              fmaf(p.z, p.z, p.w * p.w), 0.f);
    }
    __syncthreads();

    // Load R a-points into registers (coalesced float2, stride BLOCK)
    float ax[R], ay[R], mn[R];
    const int ibase = achunk * APB + threadIdx.x;
    const float2* a2p = reinterpret_cast<const float2*>(a);
    #pragma unroll
    for (int r = 0; r < R; ++r) {
        float2 p = a2p[ibase + r * BLOCK];
        ax[r] = p.x; ay[r] = p.y;
        mn[r] = 3.0e38f;
    }

    // Main loop: 512 iterations x (1 broadcast LDS read + 24 VALU)
    #pragma unroll 4
    for (int j = 0; j < MCHUNK; ++j) {
        float4 q = sb[j];
        #pragma unroll
        for (int r = 0; r < R; ++r) {
            float t = fmaf(ay[r], q.y, q.z);
            t = fmaf(ax[r], q.x, t);
            mn[r] = fminf(mn[r], t);
        }
    }

    // Add a2_i back, clamp to >= 0, combine across m-chunks via uint atomicMin
    unsigned int* dst = minbits + ((size_t)batch * 2 + dir) * NPTS;
    #pragma unroll
    for (int r = 0; r < R; ++r) {
        float val = mn[r] + fmaf(ax[r], ax[r], ay[r] * ay[r]);
        val = fmaxf(val, 0.0f);
        atomicMin(&dst[ibase + r * BLOCK], __float_as_uint(val));
    }
}

// Max-reduce each [batch,dir] row of 8192 min-d2 values.
__global__ __launch_bounds__(256) void hausdorff_max_kernel(
    const unsigned int* __restrict__ minbits, float* __restrict__ hmax /*[B][2]*/)
{
    int bd = blockIdx.x;  // batch*2 + dir, 8 blocks
    const unsigned int* src = minbits + (size_t)bd * NPTS;
    float m = 0.f;
    for (int i = threadIdx.x; i < NPTS; i += 256)
        m = fmaxf(m, __uint_as_float(src[i]));
    #pragma unroll
    for (int o = 32; o > 0; o >>= 1)
        m = fmaxf(m, __shfl_xor(m, o));
    __shared__ float sm[4];
    int wid = threadIdx.x >> 6;
    if ((threadIdx.x & 63) == 0) sm[wid] = m;
    __syncthreads();
    if (threadIdx.x == 0) {
        m = fmaxf(fmaxf(sm[0], sm[1]), fmaxf(sm[2], sm[3]));
        hmax[bd] = m;
    }
}

// Final: mean over batches of sqrt(max(h_ab, h_ba))
__global__ void hausdorff_final_kernel(const float* __restrict__ hmax,
                                       float* __restrict__ out)
{
    if (threadIdx.x == 0 && blockIdx.x == 0) {
        float s = 0.f;
        #pragma unroll
        for (int b = 0; b < NBATCH; ++b)
            s += sqrtf(fmaxf(hmax[2 * b], hmax[2 * b + 1]));
        out[0] = s * (1.0f / NBATCH);
    }
}

extern "C" void kernel_launch(void* const* d_in, const int* in_sizes, int n_in,
                              void* d_out, int out_size, void* d_ws, size_t ws_size,
                              hipStream_t stream) {
    const float* pred = (const float*)d_in[0];   // [4,8192,2] f32
    const float* targ = (const float*)d_in[1];   // [4,8192,2] f32

    unsigned int* minbits = (unsigned int*)d_ws;                    // B*2*N uints = 256 KB
    float* hmax = (float*)((char*)d_ws + (size_t)NBATCH * 2 * NPTS * sizeof(unsigned int));

    // Init min buffer to +big (0x7F7F7F7F = 3.39e38f); capturable async memset.
    hipMemsetAsync(d_ws, 0x7F, (size_t)NBATCH * 2 * NPTS * sizeof(unsigned int), stream);

    int blocks = NBATCH * 2 * (NPTS / APB) * (NPTS / MCHUNK);  // 4*2*4*16 = 512
    hipLaunchKernelGGL(hausdorff_min_kernel, dim3(blocks), dim3(BLOCK), 0, stream,
                       pred, targ, minbits);
    hipLaunchKernelGGL(hausdorff_max_kernel, dim3(NBATCH * 2), dim3(256), 0, stream,
                       minbits, hmax);
    hipLaunchKernelGGL(hausdorff_final_kernel, dim3(1), dim3(64), 0, stream,
                       hmax, (float*)d_out);
}

// Round 2
// 34.647 us; speedup vs baseline: 1.3627x; 1.3627x over previous
//
#include <hip/hip_runtime.h>
#include <math.h>

#define NPTS 8192
#define NB 4
#define SCALE (1.0f/32.0f)
#define JSPLIT 4
#define JCH (NPTS/JSPLIT)   // 2048 b-points staged per block (32 KB LDS)
#define IBLK 256            // a-points per block: 4 waves x 2 tiles x 32

typedef _Float16 half4 __attribute__((ext_vector_type(4)));
typedef float float16 __attribute__((ext_vector_type(16)));
typedef unsigned long long u64;
typedef unsigned int u32;

union H4 { half4 h; u64 u; };

// ws layout:
//   [0,       256K) : minbits u32[NB*2*NPTS]
//   [256K,    +32 ) : hmax float[8]
//   [1M,      2M  ) : AV u64[src2][khalf2][NB][NPTS]  (a-side vec halves)
//   [2M,      3M  ) : BV u64[src2][khalf2][NB][NPTS]  (b-side vec halves)

__device__ __forceinline__ float tmin16(const float16& a) {
    float t0 = fminf(fminf(a[0],  a[1]),  a[2]);
    float t1 = fminf(fminf(a[3],  a[4]),  a[5]);
    float t2 = fminf(fminf(a[6],  a[7]),  a[8]);
    float t3 = fminf(fminf(a[9],  a[10]), a[11]);
    float t4 = fminf(fminf(a[12], a[13]), a[14]);
    float u0 = fminf(fminf(t0, t1), t2);
    float u1 = fminf(fminf(t3, t4), a[15]);
    return fminf(u0, u1);
}

__global__ __launch_bounds__(256) void haus_prep(
    const float* __restrict__ pred, const float* __restrict__ targ,
    u64* __restrict__ AV, u64* __restrict__ BV, u32* __restrict__ minbits)
{
    int tid = blockIdx.x * 256 + threadIdx.x;       // 0..65535
    minbits[tid] = 0x7F7F7F7Fu;                     // +3.39e38 init for atomicMin
    int src = tid >> 15;                            // 0=pred, 1=targ
    int idx = tid & 32767;                          // batch*NPTS + pt
    const float2* in = (const float2*)(src ? targ : pred);
    float2 p = in[idx];
    float xs = p.x * SCALE, ys = p.y * SCALE;
    // A-side (point as query): [axh, axh, axl, ayh | ayh, ayl, 1, 1]
    _Float16 axh = (_Float16)xs; _Float16 axl = (_Float16)(xs - (float)axh);
    _Float16 ayh = (_Float16)ys; _Float16 ayl = (_Float16)(ys - (float)ayh);
    H4 alo, ahi;
    alo.h = (half4){axh, axh, axl, ayh};
    ahi.h = (half4){ayh, ayl, (_Float16)1.0f, (_Float16)1.0f};
    // B-side (point as target): u = -2*b', w = |b'|^2
    float ux = -2.0f * xs, uy = -2.0f * ys;
    _Float16 uxh = (_Float16)ux; _Float16 uxl = (_Float16)(ux - (float)uxh);
    _Float16 uyh = (_Float16)uy; _Float16 uyl = (_Float16)(uy - (float)uyh);
    float w = fmaf(xs, xs, ys * ys);
    _Float16 wh = (_Float16)w; _Float16 wl = (_Float16)(w - (float)wh);
    H4 blo, bhi;
    blo.h = (half4){uxh, uxl, uxh, uyh};
    bhi.h = (half4){uyl, uyh, wh, wl};
    AV[(src*2+0)*(NB*NPTS) + idx] = alo.u;
    AV[(src*2+1)*(NB*NPTS) + idx] = ahi.u;
    BV[(src*2+0)*(NB*NPTS) + idx] = blo.u;
    BV[(src*2+1)*(NB*NPTS) + idx] = bhi.u;
}

__global__ __launch_bounds__(256, 4) void haus_main(
    const float* __restrict__ pred, const float* __restrict__ targ,
    const u64* __restrict__ AV, const u64* __restrict__ BV,
    u32* __restrict__ minbits)
{
    extern __shared__ u64 sL[];                      // [2][JCH]
    int bid = blockIdx.x;                            // 1024 = 4js x 32ib x 2dir x 4b
    int jh   = bid & (JSPLIT-1); bid >>= 2;
    int iblk = bid & 31;         bid >>= 5;
    int dir  = bid & 1;          bid >>= 1;
    int batch = bid;

    int tid = threadIdx.x;
    int wave = tid >> 6, lane = tid & 63;
    int lr = lane & 31, lh = lane >> 5;
    int asrc = dir, bsrc = dir ^ 1;                  // dir0: a=pred,b=targ

    // Stage this block's j-chunk of b-side vec halves into LDS (linear, conflict-free)
    const u64* s0 = BV + (size_t)(bsrc*2+0)*(NB*NPTS) + batch*NPTS + jh*JCH;
    const u64* s1 = BV + (size_t)(bsrc*2+1)*(NB*NPTS) + batch*NPTS + jh*JCH;
    #pragma unroll
    for (int it = 0; it < JCH/256; ++it) {
        sL[it*256 + tid]       = s0[it*256 + tid];
        sL[JCH + it*256 + tid] = s1[it*256 + tid];
    }

    // Persistent R-frags (a-side): lane holds k-half (lh) of point ibase+lr
    int ibase = iblk*IBLK + wave*64;                 // 2 i-tiles: +0, +32
    const u64* av = AV + (size_t)(asrc*2+lh)*(NB*NPTS) + batch*NPTS;
    H4 r0u, r1u; r0u.u = av[ibase + lr]; r1u.u = av[ibase + 32 + lr];
    half4 R0 = r0u.h, R1 = r1u.h;

    __syncthreads();

    float mn0 = 3.0e38f, mn1 = 3.0e38f;
    const u64* lptr = sL + lh*JCH + lr;
    #pragma unroll 2
    for (int jt = 0; jt < JCH/32; ++jt) {            // 64 j-tiles of 32
        H4 lu; lu.u = lptr[jt*32];
        half4 L = lu.h;
        float16 z{};
        // D[j_row][i_col]: rows = b-points (folded in-lane), cols = a-points
        float16 a0 = __builtin_amdgcn_mfma_f32_32x32x8f16(L, R0, z, 0, 0, 0);
        float16 a1 = __builtin_amdgcn_mfma_f32_32x32x8f16(L, R1, z, 0, 0, 0);
        mn0 = fminf(mn0, tmin16(a0));
        mn1 = fminf(mn1, tmin16(a1));
    }
    // merge the two lane-halves (they hold the other 16 j-rows of the same i)
    mn0 = fminf(mn0, __shfl_xor(mn0, 32));
    mn1 = fminf(mn1, __shfl_xor(mn1, 32));

    if (lh == 0) {
        const float2* ain = (const float2*)(asrc ? targ : pred) + (size_t)batch*NPTS;
        u32* dst = minbits + ((batch*2 + dir) << 13);
        int i = ibase + lr;
        float2 p = ain[i];
        float xs = p.x*SCALE, ys = p.y*SCALE;
        float v = fmaxf(mn0 + fmaf(xs, xs, ys*ys), 0.0f);   // += a2' then clamp
        atomicMin(dst + i, __float_as_uint(v));
        p = ain[i + 32];
        xs = p.x*SCALE; ys = p.y*SCALE;
        v = fmaxf(mn1 + fmaf(xs, xs, ys*ys), 0.0f);
        atomicMin(dst + i + 32, __float_as_uint(v));
    }
}

__global__ __launch_bounds__(256) void haus_reduce(
    const u32* __restrict__ minbits, float* __restrict__ hmax)
{
    int bd = blockIdx.x;                             // batch*2+dir, 8 blocks
    const u32* src = minbits + (size_t)bd * NPTS;
    float m = 0.0f;
    for (int i = threadIdx.x; i < NPTS; i += 256)
        m = fmaxf(m, __uint_as_float(src[i]));
    #pragma unroll
    for (int o = 32; o; o >>= 1) m = fmaxf(m, __shfl_xor(m, o));
    __shared__ float sm[4];
    if ((threadIdx.x & 63) == 0) sm[threadIdx.x >> 6] = m;
    __syncthreads();
    if (threadIdx.x == 0)
        hmax[bd] = fmaxf(fmaxf(sm[0], sm[1]), fmaxf(sm[2], sm[3]));
}

__global__ void haus_final(const float* __restrict__ hmax, float* __restrict__ out)
{
    if (threadIdx.x == 0 && blockIdx.x == 0) {
        float s = 0.0f;
        #pragma unroll
        for (int b = 0; b < NB; ++b)
            s += sqrtf(fmaxf(hmax[2*b], hmax[2*b+1]));
        out[0] = s * (32.0f / NB);                   // unscale (1/s) and mean
    }
}

extern "C" void kernel_launch(void* const* d_in, const int* in_sizes, int n_in,
                              void* d_out, int out_size, void* d_ws, size_t ws_size,
                              hipStream_t stream) {
    const float* pred = (const float*)d_in[0];   // [4,8192,2] f32
    const float* targ = (const float*)d_in[1];   // [4,8192,2] f32

    u32* minbits = (u32*)d_ws;
    float* hmax  = (float*)((char*)d_ws + 262144);
    u64*  AV     = (u64*)((char*)d_ws + (1u << 20));
    u64*  BV     = (u64*)((char*)d_ws + (2u << 20));

    hipLaunchKernelGGL(haus_prep, dim3(256), dim3(256), 0, stream,
                       pred, targ, AV, BV, minbits);
    hipLaunchKernelGGL(haus_main, dim3(NB * 2 * 32 * JSPLIT), dim3(256),
                       2 * JCH * sizeof(u64), stream, pred, targ, AV, BV, minbits);
    hipLaunchKernelGGL(haus_reduce, dim3(NB * 2), dim3(256), 0, stream,
                       minbits, hmax);
    hipLaunchKernelGGL(haus_final, dim3(1), dim3(64), 0, stream,
                       hmax, (float*)d_out);
}